// Round 2
// baseline (241.844 us; speedup 1.0000x reference)
//
#include <hip/hip_runtime.h>
#include <hip/hip_bf16.h>

typedef __attribute__((ext_vector_type(4))) float f32x4;
typedef __attribute__((ext_vector_type(8))) short s16x8;

// ---------------------------------------------------------------------------
// k0: pack g_fc2_w (64,256,256) fp32 -> bf16 MFMA B-fragments, 1KB contiguous
// per fragment.  frag f = (n*8+ks)*16 + ct  (ct = col/16):
//   lane l, elem j = g2w[n][ks*32 + (l>>4)*8 + j][ct*16 + (l&15)]
// ---------------------------------------------------------------------------
__global__ __launch_bounds__(256) void k0_pack(const float* __restrict__ w2,
                                               ushort* __restrict__ out) {
  __shared__ float tile[32][257];
  const int n = blockIdx.x >> 3, ks = blockIdx.x & 7;
  const float* src = w2 + ((size_t)n * 256 + ks * 32) * 256;
  for (int i = threadIdx.x; i < 8192; i += 256)
    tile[i >> 8][i & 255] = src[i];
  __syncthreads();
#pragma unroll
  for (int q = 0; q < 4; ++q) {
    int chunk = q * 256 + threadIdx.x;
    int ct = chunk >> 6, l = chunk & 63;
    int g = l >> 4, cl = l & 15;
    s16x8 pk;
#pragma unroll
    for (int j = 0; j < 8; ++j) {
      __hip_bfloat16 h = __float2bfloat16(tile[g * 8 + j][ct * 16 + cl]);
      pk[j] = *reinterpret_cast<short*>(&h);
    }
    *reinterpret_cast<s16x8*>(out + ((size_t)(n * 8 + ks) * 1024 + chunk) * 8) = pk;
  }
}

// ---------------------------------------------------------------------------
// k1: f-path -> sparse_w (4096,64).  8 rows per block, 256 threads, grid 512.
// ---------------------------------------------------------------------------
__global__ __launch_bounds__(256) void k1_select(
    const float* __restrict__ x,
    const float* __restrict__ w1, const float* __restrict__ b1,
    const float* __restrict__ w2, const float* __restrict__ b2,
    const float* __restrict__ wsk, const float* __restrict__ bsk,
    const float* __restrict__ wg, const float* __restrict__ bg,
    const float* __restrict__ lng, const float* __restrict__ lnb,
    float* __restrict__ spw) {
  __shared__ float xs[8][64];
  __shared__ float t1[8][256];
  __shared__ float wvv[8][64];
  const int t = threadIdx.x;
  const int b0 = blockIdx.x * 8;
  if (t < 128) {
    const f32x4* xin = reinterpret_cast<const f32x4*>(x + (size_t)b0 * 64);
    reinterpret_cast<f32x4*>(&xs[0][0])[t] = xin[t];
  }
  __syncthreads();
  {  // t1[r][h] = elu(x @ f_fc1_w + b1), thread t = h
    float acc[8];
    float bias = b1[t];
#pragma unroll
    for (int r = 0; r < 8; ++r) acc[r] = bias;
    for (int n = 0; n < 64; ++n) {
      float w = w1[n * 256 + t];
#pragma unroll
      for (int r = 0; r < 8; ++r) acc[r] = fmaf(xs[r][n], w, acc[r]);
    }
#pragma unroll
    for (int r = 0; r < 8; ++r) {
      float z = acc[r];
      t1[r][t] = fmaxf(z, 0.f) + (__expf(fminf(z, 0.f)) - 1.f);
    }
  }
  __syncthreads();
  {  // h2 / skip / gate, thread = (nn = t&63, rg = t>>6), rows rg, rg+4
    const int nn = t & 63, rg = t >> 6;
    float a2[2], as_[2], ag[2];
    float bb2 = b2[nn], bbs = bsk[nn], bbg = bg[nn];
#pragma unroll
    for (int i = 0; i < 2; ++i) { a2[i] = bb2; as_[i] = bbs; ag[i] = bbg; }
    for (int h = 0; h < 256; ++h) {
      float w = w2[h * 64 + nn];
#pragma unroll
      for (int i = 0; i < 2; ++i) a2[i] = fmaf(t1[rg + 4 * i][h], w, a2[i]);
    }
    for (int m = 0; m < 64; ++m) {
      float ws_ = wsk[m * 64 + nn], wg_ = wg[m * 64 + nn];
#pragma unroll
      for (int i = 0; i < 2; ++i) {
        float xv = xs[rg + 4 * i][m];
        as_[i] = fmaf(xv, ws_, as_[i]);
        ag[i]  = fmaf(xv, wg_, ag[i]);
      }
    }
#pragma unroll
    for (int i = 0; i < 2; ++i) {
      float gt = __fdividef(1.f, 1.f + __expf(-ag[i]));
      wvv[rg + 4 * i][nn] = fmaf(gt, a2[i] - as_[i], as_[i]);
    }
  }
  __syncthreads();
  {  // LN over 64 + softmax over 64, wave handles 2 rows
    const int lane = t & 63, wid = t >> 6;
    float gl = lng[lane], bl = lnb[lane];
#pragma unroll
    for (int rr = 0; rr < 2; ++rr) {
      int r = wid * 2 + rr;
      float v = wvv[r][lane];
      float s = v;
      for (int m = 1; m < 64; m <<= 1) s += __shfl_xor(s, m);
      float mu = s * (1.f / 64.f);
      float d = v - mu;
      float q = d * d;
      for (int m = 1; m < 64; m <<= 1) q += __shfl_xor(q, m);
      float wn = d * rsqrtf(q * (1.f / 64.f) + 1e-5f) * gl + bl;
      float mx = wn;
      for (int m = 1; m < 64; m <<= 1) mx = fmaxf(mx, __shfl_xor(mx, m));
      float e = __expf(wn - mx);
      float se = e;
      for (int m = 1; m < 64; m <<= 1) se += __shfl_xor(se, m);
      spw[(size_t)(b0 + r) * 64 + lane] = __fdividef(e, se);
    }
  }
}

// ---------------------------------------------------------------------------
// k2: fused einsum + gate/skip + LN(H) + weighted accumulate.
// grid 512: bid = btile*8 + nchunk (nchunk = bid&7 -> XCD-pinned weights).
// 512 threads / 8 waves; wave w owns 64 rows x cols [w*32, w*32+32).
// B frags loaded straight from L2 (pre-packed by k0) -> registers.
// A generated into 32KB swizzled LDS.  2 barriers per ni.
// ---------------------------------------------------------------------------
__global__ __launch_bounds__(512, 4) void k2_main(
    const float* __restrict__ x,
    const ushort* __restrict__ w2p,
    const float* __restrict__ fc1w, const float* __restrict__ fc1b,
    const float* __restrict__ fc2b,
    const float* __restrict__ skw, const float* __restrict__ skb,
    const float* __restrict__ gww, const float* __restrict__ gwb,
    const float* __restrict__ lng, const float* __restrict__ lnb,
    const float* __restrict__ spw,
    float* __restrict__ comb) {
  __shared__ __align__(16) char Ab[32768];   // A tile 64x256 bf16, swizzled
  __shared__ float xs[64][9];
  __shared__ float ss[64][9];
  __shared__ float sums[2][64][2];

  const int bid = blockIdx.x;
  const int nch = bid & 7;
  const int b0  = (bid >> 3) * 64;
  const int t = threadIdx.x;
  const int lane = t & 63;
  const int w = t >> 6;          // 0..7 (col band)
  const int g = lane >> 4;
  const int cl = lane & 15;
  const int n0 = nch * 8;

  { int r = t >> 3, j = t & 7;
    xs[r][j] = x[(size_t)(b0 + r) * 64 + nch * 8 + j];
    ss[r][j] = spw[(size_t)(b0 + r) * 64 + nch * 8 + j]; }
  if (t < 128) sums[0][t >> 1][t & 1] = 0.f;

  f32x4 comb_acc[4][2];
#pragma unroll
  for (int a = 0; a < 4; ++a)
#pragma unroll
    for (int b = 0; b < 2; ++b) comb_acc[a][b] = (f32x4){0.f, 0.f, 0.f, 0.f};

  // depth-2 register prefetch of B fragments (ct=0,1 per buffer)
  s16x8 bfa[2], bfb[2];
  const s16x8* wf = reinterpret_cast<const s16x8*>(w2p);
#define BFRAG(nn, kk) (wf + (((size_t)((nn) * 8 + (kk)) * 16 + w * 2) * 64 + lane))
  { const s16x8* p = BFRAG(n0, 0); bfa[0] = p[0]; bfa[1] = p[64];
    p = BFRAG(n0, 1); bfb[0] = p[0]; bfb[1] = p[64]; }

  __syncthreads();

  for (int ni = 0; ni < 8; ++ni) {
    const int n = n0 + ni;
    // ---- A-gen: A[r][k] = elu(x[b0+r][n]*fc1w[n][k] + fc1b[n][k]) ----
    {
      const int kc = t & 31;
      const int rb = t >> 5;     // 0..15
      const float* w1p = fc1w + n * 256 + kc * 8;
      const float* b1p = fc1b + n * 256 + kc * 8;
      f32x4 wlo = *reinterpret_cast<const f32x4*>(w1p);
      f32x4 whi = *reinterpret_cast<const f32x4*>(w1p + 4);
      f32x4 blo = *reinterpret_cast<const f32x4*>(b1p);
      f32x4 bhi = *reinterpret_cast<const f32x4*>(b1p + 4);
#pragma unroll
      for (int i = 0; i < 4; ++i) {
        int r = rb + 16 * i;
        float xv = xs[r][ni];
        s16x8 pk;
#pragma unroll
        for (int j = 0; j < 4; ++j) {
          float z0 = fmaf(xv, wlo[j], blo[j]);
          float z1 = fmaf(xv, whi[j], bhi[j]);
          float e0 = fmaxf(z0, 0.f) + (__expf(fminf(z0, 0.f)) - 1.f);
          float e1 = fmaxf(z1, 0.f) + (__expf(fminf(z1, 0.f)) - 1.f);
          __hip_bfloat16 h0 = __float2bfloat16(e0);
          __hip_bfloat16 h1 = __float2bfloat16(e1);
          pk[j]     = *reinterpret_cast<short*>(&h0);
          pk[j + 4] = *reinterpret_cast<short*>(&h1);
        }
        *reinterpret_cast<s16x8*>(Ab + r * 512 + ((kc << 4) ^ ((r & 7) << 4))) = pk;
      }
    }
    __syncthreads();   // Ab ready; all waves past previous epilogue

    f32x4 acc[4][2];
#pragma unroll
    for (int a = 0; a < 4; ++a)
#pragma unroll
      for (int b = 0; b < 2; ++b) acc[a][b] = (f32x4){0.f, 0.f, 0.f, 0.f};

#pragma unroll
    for (int ks = 0; ks < 8; ++ks) {
      s16x8* cur = (ks & 1) ? bfb : bfa;
      s16x8 af[4];
#pragma unroll
      for (int mt = 0; mt < 4; ++mt) {
        int row = mt * 16 + cl;
        af[mt] = *reinterpret_cast<const s16x8*>(
            Ab + row * 512 + (((ks * 4 + g) << 4) ^ ((row & 7) << 4)));
      }
#pragma unroll
      for (int mt = 0; mt < 4; ++mt) {
        acc[mt][0] = __builtin_amdgcn_mfma_f32_16x16x32_bf16(af[mt], cur[0],
                                                             acc[mt][0], 0, 0, 0);
        acc[mt][1] = __builtin_amdgcn_mfma_f32_16x16x32_bf16(af[mt], cur[1],
                                                             acc[mt][1], 0, 0, 0);
      }
      // roll the prefetch: ks+2 of this n, or ks=0,1 of the next n
      if (ks < 6) {
        const s16x8* p = BFRAG(n, ks + 2); cur[0] = p[0]; cur[1] = p[64];
      } else if (ni < 7) {
        const s16x8* p = BFRAG(n + 1, ks - 6); cur[0] = p[0]; cur[1] = p[64];
      }
    }

    // ---- epilogue: gate mix, LN over H=256, weighted accumulate ----
    const int par = ni & 1;
    {
      float rsum[4][4], rsq[4][4];
#pragma unroll
      for (int mt = 0; mt < 4; ++mt)
#pragma unroll
        for (int rg = 0; rg < 4; ++rg) { rsum[mt][rg] = 0.f; rsq[mt][rg] = 0.f; }
#pragma unroll
      for (int ct = 0; ct < 2; ++ct) {
        int c = w * 32 + ct * 16 + cl;
        float f2b = fc2b[n * 256 + c];
        float sw_ = skw[n * 256 + c], sb_ = skb[n * 256 + c];
        float gw_ = gww[n * 256 + c], gb_ = gwb[n * 256 + c];
#pragma unroll
        for (int mt = 0; mt < 4; ++mt)
#pragma unroll
          for (int rg = 0; rg < 4; ++rg) {
            float hv = acc[mt][ct][rg] + f2b;
            float xr = xs[mt * 16 + g * 4 + rg][ni];
            float sk = fmaf(xr, sw_, sb_);
            float zg = fmaf(xr, gw_, gb_);
            float gv = __fdividef(1.f, 1.f + __expf(-zg));
            float p = fmaf(gv, hv - sk, sk);
            acc[mt][ct][rg] = p;
            rsum[mt][rg] += p;
            rsq[mt][rg] = fmaf(p, p, rsq[mt][rg]);
          }
      }
#pragma unroll
      for (int mt = 0; mt < 4; ++mt)
#pragma unroll
        for (int rg = 0; rg < 4; ++rg) {
#pragma unroll
          for (int m = 1; m < 16; m <<= 1) {
            rsum[mt][rg] += __shfl_xor(rsum[mt][rg], m);
            rsq[mt][rg]  += __shfl_xor(rsq[mt][rg], m);
          }
        }
      if (cl == 0) {
#pragma unroll
        for (int mt = 0; mt < 4; ++mt)
#pragma unroll
          for (int rg = 0; rg < 4; ++rg) {
            int row = mt * 16 + g * 4 + rg;
            atomicAdd(&sums[par][row][0], rsum[mt][rg]);
            atomicAdd(&sums[par][row][1], rsq[mt][rg]);
          }
      }
    }
    if (t < 128) sums[par ^ 1][t >> 1][t & 1] = 0.f;  // zero parity for ni+1
    __syncthreads();   // sums ready; also fences Ab overwrite for ni+1

    // pass 2: normalize + softmax-weighted accumulate
#pragma unroll
    for (int mt = 0; mt < 4; ++mt)
#pragma unroll
      for (int rg = 0; rg < 4; ++rg) {
        int row = mt * 16 + g * 4 + rg;
        float s0 = sums[par][row][0], s1 = sums[par][row][1];
        float mu = s0 * (1.f / 256.f);
        float rs = rsqrtf(fmaxf(s1 * (1.f / 256.f) - mu * mu, 0.f) + 1e-5f);
        float sv = ss[row][ni];
#pragma unroll
        for (int ct = 0; ct < 2; ++ct) {
          int c = w * 32 + ct * 16 + cl;
          float gl = lng[n * 256 + c], bl = lnb[n * 256 + c];
          float p = acc[mt][ct][rg];
          comb_acc[mt][ct][rg] =
              fmaf(sv, fmaf((p - mu) * rs, gl, bl), comb_acc[mt][ct][rg]);
        }
      }
  }
#undef BFRAG

#pragma unroll
  for (int mt = 0; mt < 4; ++mt)
#pragma unroll
    for (int rg = 0; rg < 4; ++rg) {
      int row = b0 + mt * 16 + g * 4 + rg;
#pragma unroll
      for (int ct = 0; ct < 2; ++ct) {
        int c = w * 32 + ct * 16 + cl;
        atomicAdd(&comb[(size_t)row * 256 + c], comb_acc[mt][ct][rg]);
      }
    }
}

// ---------------------------------------------------------------------------
extern "C" void kernel_launch(void* const* d_in, const int* in_sizes, int n_in,
                              void* d_out, int out_size, void* d_ws, size_t ws_size,
                              hipStream_t stream) {
  const float* x   = (const float*)d_in[0];
  const float* f1w = (const float*)d_in[1];
  const float* f1b = (const float*)d_in[2];
  const float* f2w = (const float*)d_in[3];
  const float* f2b = (const float*)d_in[4];
  const float* fsw = (const float*)d_in[5];
  const float* fsb = (const float*)d_in[6];
  const float* fgw = (const float*)d_in[7];
  const float* fgb = (const float*)d_in[8];
  const float* flg = (const float*)d_in[9];
  const float* flb = (const float*)d_in[10];
  const float* g1w = (const float*)d_in[11];
  const float* g1b = (const float*)d_in[12];
  const float* g2w = (const float*)d_in[13];
  const float* g2b = (const float*)d_in[14];
  const float* gsw = (const float*)d_in[15];
  const float* gsb = (const float*)d_in[16];
  const float* ggw = (const float*)d_in[17];
  const float* ggb = (const float*)d_in[18];
  const float* glg = (const float*)d_in[19];
  const float* glb = (const float*)d_in[20];

  float* out  = (float*)d_out;
  float* comb = out;                          // (4096,256)
  float* spw  = out + (size_t)4096 * 256;     // (4096,64)
  ushort* w2p = (ushort*)d_ws;                // 8.4 MB packed bf16 B-frags

  hipMemsetAsync(comb, 0, (size_t)4096 * 256 * sizeof(float), stream);
  k0_pack<<<512, 256, 0, stream>>>(g2w, w2p);
  k1_select<<<512, 256, 0, stream>>>(x, f1w, f1b, f2w, f2b, fsw, fsb,
                                     fgw, fgb, flg, flb, spw);
  k2_main<<<512, 512, 0, stream>>>(x, w2p, g1w, g1b, g2b, gsw, gsb,
                                   ggw, ggb, glg, glb, spw, comb);
}

// Round 3
// 200.038 us; speedup vs baseline: 1.2090x; 1.2090x over previous
//
#include <hip/hip_runtime.h>
#include <hip/hip_bf16.h>

typedef __attribute__((ext_vector_type(4))) float f32x4;
typedef __attribute__((ext_vector_type(8))) short s16x8;

// ---------------------------------------------------------------------------
// k0: pack g_fc2_w (64,256,256) fp32 -> bf16 MFMA B-fragments, 1KB contiguous
// per fragment.  frag f = (n*8+ks)*16 + ct  (ct = col/16):
//   lane l, elem j = g2w[n][ks*32 + (l>>4)*8 + j][ct*16 + (l&15)]
// ---------------------------------------------------------------------------
__global__ __launch_bounds__(256) void k0_pack(const float* __restrict__ w2,
                                               ushort* __restrict__ out) {
  __shared__ float tile[32][257];
  const int n = blockIdx.x >> 3, ks = blockIdx.x & 7;
  const float* src = w2 + ((size_t)n * 256 + ks * 32) * 256;
  for (int i = threadIdx.x; i < 8192; i += 256)
    tile[i >> 8][i & 255] = src[i];
  __syncthreads();
#pragma unroll
  for (int q = 0; q < 4; ++q) {
    int chunk = q * 256 + threadIdx.x;
    int ct = chunk >> 6, l = chunk & 63;
    int g = l >> 4, cl = l & 15;
    s16x8 pk;
#pragma unroll
    for (int j = 0; j < 8; ++j) {
      __hip_bfloat16 h = __float2bfloat16(tile[g * 8 + j][ct * 16 + cl]);
      pk[j] = *reinterpret_cast<short*>(&h);
    }
    *reinterpret_cast<s16x8*>(out + ((size_t)(n * 8 + ks) * 1024 + chunk) * 8) = pk;
  }
}

// ---------------------------------------------------------------------------
// k1: f-path -> sparse_w (4096,64).  8 rows per block, 256 threads, grid 512.
// ---------------------------------------------------------------------------
__global__ __launch_bounds__(256) void k1_select(
    const float* __restrict__ x,
    const float* __restrict__ w1, const float* __restrict__ b1,
    const float* __restrict__ w2, const float* __restrict__ b2,
    const float* __restrict__ wsk, const float* __restrict__ bsk,
    const float* __restrict__ wg, const float* __restrict__ bg,
    const float* __restrict__ lng, const float* __restrict__ lnb,
    float* __restrict__ spw) {
  __shared__ float xs[8][64];
  __shared__ float t1[8][256];
  __shared__ float wvv[8][64];
  const int t = threadIdx.x;
  const int b0 = blockIdx.x * 8;
  if (t < 128) {
    const f32x4* xin = reinterpret_cast<const f32x4*>(x + (size_t)b0 * 64);
    reinterpret_cast<f32x4*>(&xs[0][0])[t] = xin[t];
  }
  __syncthreads();
  {  // t1[r][h] = elu(x @ f_fc1_w + b1), thread t = h
    float acc[8];
    float bias = b1[t];
#pragma unroll
    for (int r = 0; r < 8; ++r) acc[r] = bias;
    for (int n = 0; n < 64; ++n) {
      float w = w1[n * 256 + t];
#pragma unroll
      for (int r = 0; r < 8; ++r) acc[r] = fmaf(xs[r][n], w, acc[r]);
    }
#pragma unroll
    for (int r = 0; r < 8; ++r) {
      float z = acc[r];
      t1[r][t] = fmaxf(z, 0.f) + (__expf(fminf(z, 0.f)) - 1.f);
    }
  }
  __syncthreads();
  {  // h2 / skip / gate, thread = (nn = t&63, rg = t>>6), rows rg, rg+4
    const int nn = t & 63, rg = t >> 6;
    float a2[2], as_[2], ag[2];
    float bb2 = b2[nn], bbs = bsk[nn], bbg = bg[nn];
#pragma unroll
    for (int i = 0; i < 2; ++i) { a2[i] = bb2; as_[i] = bbs; ag[i] = bbg; }
    for (int h = 0; h < 256; ++h) {
      float w = w2[h * 64 + nn];
#pragma unroll
      for (int i = 0; i < 2; ++i) a2[i] = fmaf(t1[rg + 4 * i][h], w, a2[i]);
    }
    for (int m = 0; m < 64; ++m) {
      float ws_ = wsk[m * 64 + nn], wg_ = wg[m * 64 + nn];
#pragma unroll
      for (int i = 0; i < 2; ++i) {
        float xv = xs[rg + 4 * i][m];
        as_[i] = fmaf(xv, ws_, as_[i]);
        ag[i]  = fmaf(xv, wg_, ag[i]);
      }
    }
#pragma unroll
    for (int i = 0; i < 2; ++i) {
      float gt = __fdividef(1.f, 1.f + __expf(-ag[i]));
      wvv[rg + 4 * i][nn] = fmaf(gt, a2[i] - as_[i], as_[i]);
    }
  }
  __syncthreads();
  {  // LN over 64 + softmax over 64, wave handles 2 rows
    const int lane = t & 63, wid = t >> 6;
    float gl = lng[lane], bl = lnb[lane];
#pragma unroll
    for (int rr = 0; rr < 2; ++rr) {
      int r = wid * 2 + rr;
      float v = wvv[r][lane];
      float s = v;
      for (int m = 1; m < 64; m <<= 1) s += __shfl_xor(s, m);
      float mu = s * (1.f / 64.f);
      float d = v - mu;
      float q = d * d;
      for (int m = 1; m < 64; m <<= 1) q += __shfl_xor(q, m);
      float wn = d * rsqrtf(q * (1.f / 64.f) + 1e-5f) * gl + bl;
      float mx = wn;
      for (int m = 1; m < 64; m <<= 1) mx = fmaxf(mx, __shfl_xor(mx, m));
      float e = __expf(wn - mx);
      float se = e;
      for (int m = 1; m < 64; m <<= 1) se += __shfl_xor(se, m);
      spw[(size_t)(b0 + r) * 64 + lane] = __fdividef(e, se);
    }
  }
}

// ---------------------------------------------------------------------------
// k2: fused einsum + gate/skip + LN(H) + weighted accumulate.
// grid 512: bid = btile*8 + nchunk (nchunk = bid&7 -> XCD-pinned weights).
// 512 threads / 8 waves; wave w owns 64 rows x cols [w*32, w*32+32).
// B frags loaded straight from L2 (pre-packed by k0) -> registers.
// A generated into 32KB swizzled LDS.  2 barriers per ni.
// Register budget (128/wave, 2 blocks/CU): comb_acc 32 + acc 32 + bf 16
// + af 16 transient; B prefetch for n issued at ni-top (dead in epilogue).
// ---------------------------------------------------------------------------
__global__ __launch_bounds__(512, 2) void k2_main(
    const float* __restrict__ x,
    const ushort* __restrict__ w2p,
    const float* __restrict__ fc1w, const float* __restrict__ fc1b,
    const float* __restrict__ fc2b,
    const float* __restrict__ skw, const float* __restrict__ skb,
    const float* __restrict__ gww, const float* __restrict__ gwb,
    const float* __restrict__ lng, const float* __restrict__ lnb,
    const float* __restrict__ spw,
    float* __restrict__ comb) {
  __shared__ __align__(16) char Ab[32768];   // A tile 64x256 bf16, swizzled
  __shared__ float xs[64][9];
  __shared__ float ss[64][9];
  __shared__ float sums[2][64][2];

  const int bid = blockIdx.x;
  const int nch = bid & 7;
  const int b0  = (bid >> 3) * 64;
  const int t = threadIdx.x;
  const int lane = t & 63;
  const int w = t >> 6;          // 0..7 (col band)
  const int g = lane >> 4;
  const int cl = lane & 15;
  const int n0 = nch * 8;

  { int r = t >> 3, j = t & 7;
    xs[r][j] = x[(size_t)(b0 + r) * 64 + nch * 8 + j];
    ss[r][j] = spw[(size_t)(b0 + r) * 64 + nch * 8 + j]; }
  if (t < 128) sums[0][t >> 1][t & 1] = 0.f;

  f32x4 comb_acc[4][2];
#pragma unroll
  for (int a = 0; a < 4; ++a)
#pragma unroll
    for (int b = 0; b < 2; ++b) comb_acc[a][b] = (f32x4){0.f, 0.f, 0.f, 0.f};

  const s16x8* wf = reinterpret_cast<const s16x8*>(w2p);
#define BFRAG(nn, kk) (wf + (((size_t)((nn) * 8 + (kk)) * 16 + w * 2) * 64 + lane))

  __syncthreads();

  for (int ni = 0; ni < 8; ++ni) {
    const int n = n0 + ni;
    // ---- issue B prefetch for ks=0,1 of THIS n (covered by A-gen) ----
    s16x8 bfa[2], bfb[2];
    { const s16x8* p = BFRAG(n, 0); bfa[0] = p[0]; bfa[1] = p[64];
      p = BFRAG(n, 1); bfb[0] = p[0]; bfb[1] = p[64]; }

    // ---- A-gen: A[r][k] = elu(x[b0+r][n]*fc1w[n][k] + fc1b[n][k]) ----
    {
      const int kc = t & 31;
      const int rb = t >> 5;     // 0..15
      const float* w1p = fc1w + n * 256 + kc * 8;
      const float* b1p = fc1b + n * 256 + kc * 8;
      f32x4 wlo = *reinterpret_cast<const f32x4*>(w1p);
      f32x4 whi = *reinterpret_cast<const f32x4*>(w1p + 4);
      f32x4 blo = *reinterpret_cast<const f32x4*>(b1p);
      f32x4 bhi = *reinterpret_cast<const f32x4*>(b1p + 4);
#pragma unroll
      for (int i = 0; i < 4; ++i) {
        int r = rb + 16 * i;
        float xv = xs[r][ni];
        s16x8 pk;
#pragma unroll
        for (int j = 0; j < 4; ++j) {
          float z0 = fmaf(xv, wlo[j], blo[j]);
          float z1 = fmaf(xv, whi[j], bhi[j]);
          float e0 = fmaxf(z0, 0.f) + (__expf(fminf(z0, 0.f)) - 1.f);
          float e1 = fmaxf(z1, 0.f) + (__expf(fminf(z1, 0.f)) - 1.f);
          __hip_bfloat16 h0 = __float2bfloat16(e0);
          __hip_bfloat16 h1 = __float2bfloat16(e1);
          pk[j]     = *reinterpret_cast<short*>(&h0);
          pk[j + 4] = *reinterpret_cast<short*>(&h1);
        }
        *reinterpret_cast<s16x8*>(Ab + r * 512 + ((kc << 4) ^ ((r & 7) << 4))) = pk;
      }
    }
    __syncthreads();   // Ab ready; all waves past previous pass-2

    f32x4 acc[4][2];
#pragma unroll
    for (int a = 0; a < 4; ++a)
#pragma unroll
      for (int b = 0; b < 2; ++b) acc[a][b] = (f32x4){0.f, 0.f, 0.f, 0.f};

#pragma unroll
    for (int ks = 0; ks < 8; ++ks) {
      s16x8* cur = (ks & 1) ? bfb : bfa;
      s16x8 af[4];
#pragma unroll
      for (int mt = 0; mt < 4; ++mt) {
        int row = mt * 16 + cl;
        af[mt] = *reinterpret_cast<const s16x8*>(
            Ab + row * 512 + (((ks * 4 + g) << 4) ^ ((row & 7) << 4)));
      }
#pragma unroll
      for (int mt = 0; mt < 4; ++mt) {
        acc[mt][0] = __builtin_amdgcn_mfma_f32_16x16x32_bf16(af[mt], cur[0],
                                                             acc[mt][0], 0, 0, 0);
        acc[mt][1] = __builtin_amdgcn_mfma_f32_16x16x32_bf16(af[mt], cur[1],
                                                             acc[mt][1], 0, 0, 0);
      }
      // roll the prefetch within this n only
      if (ks < 6) {
        const s16x8* p = BFRAG(n, ks + 2); cur[0] = p[0]; cur[1] = p[64];
      }
    }

    // ---- epilogue pass 1: gate mix + row sums (mt-outer, low reg) ----
    const int par = ni & 1;
    {
      const int c0 = w * 32 + cl, c1 = c0 + 16;
      const float f2b0 = fc2b[n * 256 + c0], f2b1 = fc2b[n * 256 + c1];
      const float sw0 = skw[n * 256 + c0], sw1 = skw[n * 256 + c1];
      const float sb0 = skb[n * 256 + c0], sb1 = skb[n * 256 + c1];
      const float gw0 = gww[n * 256 + c0], gw1 = gww[n * 256 + c1];
      const float gb0 = gwb[n * 256 + c0], gb1 = gwb[n * 256 + c1];
#pragma unroll
      for (int mt = 0; mt < 4; ++mt) {
        float rsum[4], rsq[4];
#pragma unroll
        for (int rg = 0; rg < 4; ++rg) {
          float xr = xs[mt * 16 + g * 4 + rg][ni];
          float hv0 = acc[mt][0][rg] + f2b0;
          float sk0 = fmaf(xr, sw0, sb0);
          float gv0 = __fdividef(1.f, 1.f + __expf(-fmaf(xr, gw0, gb0)));
          float p0 = fmaf(gv0, hv0 - sk0, sk0);
          float hv1 = acc[mt][1][rg] + f2b1;
          float sk1 = fmaf(xr, sw1, sb1);
          float gv1 = __fdividef(1.f, 1.f + __expf(-fmaf(xr, gw1, gb1)));
          float p1 = fmaf(gv1, hv1 - sk1, sk1);
          acc[mt][0][rg] = p0;
          acc[mt][1][rg] = p1;
          rsum[rg] = p0 + p1;
          rsq[rg] = fmaf(p0, p0, p1 * p1);
        }
#pragma unroll
        for (int rg = 0; rg < 4; ++rg) {
#pragma unroll
          for (int m = 1; m < 16; m <<= 1) {
            rsum[rg] += __shfl_xor(rsum[rg], m);
            rsq[rg]  += __shfl_xor(rsq[rg], m);
          }
        }
        if (cl == 0) {
#pragma unroll
          for (int rg = 0; rg < 4; ++rg) {
            int row = mt * 16 + g * 4 + rg;
            atomicAdd(&sums[par][row][0], rsum[rg]);
            atomicAdd(&sums[par][row][1], rsq[rg]);
          }
        }
      }
    }
    if (t < 128) sums[par ^ 1][t >> 1][t & 1] = 0.f;  // zero parity for ni+1
    __syncthreads();   // sums ready

    // ---- pass 2: normalize + softmax-weighted accumulate ----
#pragma unroll
    for (int mt = 0; mt < 4; ++mt)
#pragma unroll
      for (int rg = 0; rg < 4; ++rg) {
        int row = mt * 16 + g * 4 + rg;
        float s0 = sums[par][row][0], s1 = sums[par][row][1];
        float mu = s0 * (1.f / 256.f);
        float rs = rsqrtf(fmaxf(s1 * (1.f / 256.f) - mu * mu, 0.f) + 1e-5f);
        float sv = ss[row][ni];
#pragma unroll
        for (int ct = 0; ct < 2; ++ct) {
          int c = w * 32 + ct * 16 + cl;
          float gl = lng[n * 256 + c], bl = lnb[n * 256 + c];
          float p = acc[mt][ct][rg];
          comb_acc[mt][ct][rg] =
              fmaf(sv, fmaf((p - mu) * rs, gl, bl), comb_acc[mt][ct][rg]);
        }
      }
  }
#undef BFRAG

#pragma unroll
  for (int mt = 0; mt < 4; ++mt)
#pragma unroll
    for (int rg = 0; rg < 4; ++rg) {
      int row = b0 + mt * 16 + g * 4 + rg;
#pragma unroll
      for (int ct = 0; ct < 2; ++ct) {
        int c = w * 32 + ct * 16 + cl;
        atomicAdd(&comb[(size_t)row * 256 + c], comb_acc[mt][ct][rg]);
      }
    }
}

// ---------------------------------------------------------------------------
extern "C" void kernel_launch(void* const* d_in, const int* in_sizes, int n_in,
                              void* d_out, int out_size, void* d_ws, size_t ws_size,
                              hipStream_t stream) {
  const float* x   = (const float*)d_in[0];
  const float* f1w = (const float*)d_in[1];
  const float* f1b = (const float*)d_in[2];
  const float* f2w = (const float*)d_in[3];
  const float* f2b = (const float*)d_in[4];
  const float* fsw = (const float*)d_in[5];
  const float* fsb = (const float*)d_in[6];
  const float* fgw = (const float*)d_in[7];
  const float* fgb = (const float*)d_in[8];
  const float* flg = (const float*)d_in[9];
  const float* flb = (const float*)d_in[10];
  const float* g1w = (const float*)d_in[11];
  const float* g1b = (const float*)d_in[12];
  const float* g2w = (const float*)d_in[13];
  const float* g2b = (const float*)d_in[14];
  const float* gsw = (const float*)d_in[15];
  const float* gsb = (const float*)d_in[16];
  const float* ggw = (const float*)d_in[17];
  const float* ggb = (const float*)d_in[18];
  const float* glg = (const float*)d_in[19];
  const float* glb = (const float*)d_in[20];

  float* out  = (float*)d_out;
  float* comb = out;                          // (4096,256)
  float* spw  = out + (size_t)4096 * 256;     // (4096,64)
  ushort* w2p = (ushort*)d_ws;                // 8.4 MB packed bf16 B-frags

  hipMemsetAsync(comb, 0, (size_t)4096 * 256 * sizeof(float), stream);
  k0_pack<<<512, 256, 0, stream>>>(g2w, w2p);
  k1_select<<<512, 256, 0, stream>>>(x, f1w, f1b, f2w, f2b, fsw, fsb,
                                     fgw, fgb, flg, flb, spw);
  k2_main<<<512, 512, 0, stream>>>(x, w2p, g1w, g1b, g2b, gsw, gsb,
                                   ggw, ggb, glg, glb, spw, comb);
}